// Round 14
// baseline (1737.653 us; speedup 1.0000x reference)
//
#include <hip/hip_runtime.h>
#include <cstdint>
#include <cstddef>

// GGNN on MI355X. Round 14: r12 base (16x16 core, fused u5gf, absmax
// bit-verified 0.02490234). ONE change: gemf (adjf+densef) LDS shrunk
// 64KB -> 48KB via asymmetric buffering (A single-buffered 16KB, B
// double-buffered 32KB; per kt: STG_A(kt), STG_B(kt+1), vmcnt(4) drains
// exactly {B(kt), A(kt)} leaving B(kt+1) in flight) -> 3 blocks/CU
// (was 2). Per-element accumulation order unchanged -> bit-identical.
// r13 lesson: 32x32 MFMA read pattern has intrinsic bank conflicts with
// 32-elem-row planes (4.2M) — 16x16 core retained.
// Layouts:
//   A2f [2048: Ain|Aout][ l0(1024) | l1'(1024) ]   (l1 pre-scaled 2^11)
//   hN2f[b*128+d][ l0 | l1' ]
//   X2  [n*32+b][ l0: m_in(128) m_out(128) h(128) | l1' same ]  (LDX 768)
//   Wsm [384: w3|w4|w5][ l0(256)|l1'(256) ]; u3wb/u5wb [128][ l0|l1' (128) ]

typedef _Float16 f16;
typedef __attribute__((ext_vector_type(8))) _Float16 f16x8;
typedef __attribute__((ext_vector_type(4))) float f32x4;

#define LDX 768
#define LDH 2048
#define CSCL 4.8828125e-4f  // 2^-11

static __device__ __forceinline__ void gload16(const void* g, void* l) {
  __builtin_amdgcn_global_load_lds(
      (const __attribute__((address_space(1))) void*)g,
      (__attribute__((address_space(3))) void*)l, 16, 0, 0);
}

static __device__ __forceinline__ float sigmoidf_(float x) {
  return 1.f / (1.f + expf(-x));
}

static __device__ __forceinline__ unsigned short bc16(f16 x) {
  return __builtin_bit_cast(unsigned short, x);
}

// split v into l0 + l1*2^-11 (l1 stored scaled; avoids f16 subnormals)
static __device__ __forceinline__ void split2(float v, f16& l0, f16& l1) {
  l0 = (f16)v;
  l1 = (f16)((v - (float)l0) * 2048.0f);
}

#define ACCZ4(a)                                   \
  _Pragma("unroll") for (int i_ = 0; i_ < 4; ++i_) \
  _Pragma("unroll") for (int j_ = 0; j_ < 4; ++j_) a[i_][j_] = {0.f, 0.f, 0.f, 0.f};

// ======== 2-limb f16 3-product GEMM core, 128x128 tile, 4 waves (2Mx2N,
// wave 64x64, 16x16x32 MFMA). LDS 48KB: A single-buf (2 limb planes
// [128][32] = 16KB) + B dbuf (2 x 16KB). Per kt: issue A(kt), issue
// B(kt+1)->buf^1, vmcnt(4) = wait {B(kt), A(kt)}, keep B(kt+1) in flight.
static __device__ __forceinline__ void gemf(const f16* __restrict__ A, int lda,
                                            int aLS, int abase,
                                            const f16* __restrict__ B, int ldb,
                                            int bLS, int nkt, f16* lds,
                                            f32x4 (&aM)[4][4], f32x4 (&aC)[4][4]) {
  const int t = threadIdx.x;
  const int wave = t >> 6, lane = t & 63;
  const int wr = wave >> 1, wn = wave & 1;
  const int frow = lane & 15;
  const int fk = lane >> 4;
  const int sl = fk ^ ((frow >> 1) & 3);
  const int gs = (t & 3) ^ ((t >> 3) & 3);
  f16* ldsA = lds;         // 8192 f16: limb planes at 0, 4096
  f16* ldsB = lds + 8192;  // 2 bufs x 8192 f16

#define STGA(kt)                                                              \
  _Pragma("unroll") for (int lb = 0; lb < 2; ++lb)                            \
  _Pragma("unroll") for (int g = 0; g < 2; ++g) {                             \
    const int row_ = g * 64 + (t >> 2);                                       \
    gload16(A + (size_t)row_ * lda + abase + lb * aLS + (kt) * 32 + gs * 8,   \
            ldsA + lb * 4096 + g * 2048 + wave * 512);                        \
  }
#define STGB(buf, kt)                                                         \
  _Pragma("unroll") for (int lb = 0; lb < 2; ++lb)                            \
  _Pragma("unroll") for (int g = 0; g < 2; ++g) {                             \
    const int row_ = g * 64 + (t >> 2);                                       \
    gload16(B + (size_t)row_ * ldb + lb * bLS + (kt) * 32 + gs * 8,           \
            ldsB + (buf) * 8192 + lb * 4096 + g * 2048 + wave * 512);         \
  }

  STGB(0, 0);
  for (int kt = 0; kt < nkt; ++kt) {
    const int cur = kt & 1;
    STGA(kt);  // issued before B(kt+1) so vmcnt(4) covers it
    if (kt + 1 < nkt) {
      STGB(cur ^ 1, kt + 1);
      asm volatile("s_waitcnt vmcnt(4)" ::: "memory");  // B(kt)+A(kt) landed
    } else {
      asm volatile("s_waitcnt vmcnt(0)" ::: "memory");
    }
    __builtin_amdgcn_s_barrier();
    asm volatile("" ::: "memory");

    const f16* bp = ldsB + cur * 8192;
    f16x8 a0[4], a1[4], b0[4], b1[4];
#pragma unroll
    for (int nf = 0; nf < 4; ++nf) {
      const int row = wn * 64 + nf * 16 + frow;
      b0[nf] = *(const f16x8*)&bp[row * 32 + sl * 8];
      b1[nf] = *(const f16x8*)&bp[4096 + row * 32 + sl * 8];
    }
#pragma unroll
    for (int mf = 0; mf < 4; ++mf) {
      const int row = wr * 64 + mf * 16 + frow;
      a0[mf] = *(const f16x8*)&ldsA[row * 32 + sl * 8];
      a1[mf] = *(const f16x8*)&ldsA[4096 + row * 32 + sl * 8];
    }
    __builtin_amdgcn_s_setprio(1);
#pragma unroll
    for (int mf = 0; mf < 4; ++mf)
#pragma unroll
      for (int nf = 0; nf < 4; ++nf) {
        aC[mf][nf] = __builtin_amdgcn_mfma_f32_16x16x32_f16(a0[mf], b1[nf],
                                                            aC[mf][nf], 0, 0, 0);
        aC[mf][nf] = __builtin_amdgcn_mfma_f32_16x16x32_f16(a1[mf], b0[nf],
                                                            aC[mf][nf], 0, 0, 0);
      }
#pragma unroll
    for (int mf = 0; mf < 4; ++mf)
#pragma unroll
      for (int nf = 0; nf < 4; ++nf)
        aM[mf][nf] = __builtin_amdgcn_mfma_f32_16x16x32_f16(a0[mf], b0[nf],
                                                            aM[mf][nf], 0, 0, 0);
    __builtin_amdgcn_s_setprio(0);
    asm volatile("" ::: "memory");
    __builtin_amdgcn_s_barrier();  // reads done -> ldsA / ldsB[cur] reusable
  }
#undef STGA
#undef STGB
}

// ================= adjacency: M=2048(in|out), N=4096, K=1024
__global__ __launch_bounds__(256, 3) void adjf(const f16* __restrict__ A2f,
                                               const f16* __restrict__ hN2f,
                                               f16* __restrict__ X2) {
  __shared__ f16 lds[24576];  // 48KB -> 3 blocks/CU
  const int m0 = blockIdx.y * 128;
  const int n0 = blockIdx.x * 128;
  f32x4 aM[4][4], aC[4][4];
  ACCZ4(aM);
  ACCZ4(aC);
  gemf(A2f + (size_t)m0 * LDH, LDH, 1024, 0, hN2f + (size_t)n0 * LDH, LDH, 1024,
       32, lds, aM, aC);

  const int lane = threadIdx.x & 63, wave = threadIdx.x >> 6;
  const int rb = m0 + (wave >> 1) * 64 + (lane >> 4) * 4;
  const int cb = n0 + (wave & 1) * 64 + (lane & 15);
#pragma unroll
  for (int mf = 0; mf < 4; ++mf)
#pragma unroll
    for (int nf = 0; nf < 4; ++nf)
#pragma unroll
      for (int j = 0; j < 4; ++j) {
        const int gr = rb + mf * 16 + j;
        const int gc = cb + nf * 16;
        const float v = aM[mf][nf][j] + aC[mf][nf][j] * CSCL;
        const int node = gr & 1023;
        const int coff = (gr >> 10) * 128;  // 0: m_in, 128: m_out
        const int bb = gc >> 7, d = gc & 127;
        f16* px = X2 + ((size_t)node * 32 + bb) * LDX + coff + d;
        f16 l0, l1;
        split2(v, l0, l1);
        px[0] = l0;
        px[384] = l1;
      }
}

// ================= dense (r12 flow): bx<3 -> pre[.][bx*128..]; bx==3 -> u3f
__global__ __launch_bounds__(256, 3) void densef(const f16* __restrict__ X2,
                                                 const f16* __restrict__ Wsm,
                                                 const f16* __restrict__ u3wb,
                                                 const float* __restrict__ u3b,
                                                 float* __restrict__ pre,
                                                 float* __restrict__ u3f) {
  __shared__ f16 lds[24576];
  const int m0 = blockIdx.y * 128;
  const int bx = blockIdx.x;
  f32x4 aM[4][4], aC[4][4];
  ACCZ4(aM);
  ACCZ4(aC);
  const int lane = threadIdx.x & 63, wave = threadIdx.x >> 6;
  const int rb = m0 + (wave >> 1) * 64 + (lane >> 4) * 4;
  const int cb = (wave & 1) * 64 + (lane & 15);
  if (bx < 3) {
    gemf(X2 + (size_t)m0 * LDX, LDX, 384, 0, Wsm + (size_t)bx * 128 * 512, 512, 256,
         8, lds, aM, aC);
#pragma unroll
    for (int mf = 0; mf < 4; ++mf)
#pragma unroll
      for (int nf = 0; nf < 4; ++nf)
#pragma unroll
        for (int j = 0; j < 4; ++j)
          pre[(size_t)(rb + mf * 16 + j) * 384 + bx * 128 + cb + nf * 16] =
              aM[mf][nf][j] + aC[mf][nf][j] * CSCL;
  } else {
    gemf(X2 + (size_t)m0 * LDX, LDX, 384, 256, u3wb, 256, 128, 4, lds, aM, aC);
#pragma unroll
    for (int mf = 0; mf < 4; ++mf)
#pragma unroll
      for (int nf = 0; nf < 4; ++nf)
#pragma unroll
        for (int j = 0; j < 4; ++j) {
          const int gc = cb + nf * 16;
          const float v = aM[mf][nf][j] + aC[mf][nf][j] * CSCL;
          // np: u3 = (h@u3w^T) + u3b, rounded once
          u3f[(size_t)(rb + mf * 16 + j) * 128 + gc] = v + u3b[gc];
        }
  }
}

// ================= u5gf: fused ew1 + u5 GEMM + ew2 (r12-verified, unchanged)
__global__ __launch_bounds__(256, 1) void u5gf(const f16* __restrict__ u5wb,
                                               const float* __restrict__ pre,
                                               const float* __restrict__ u3f,
                                               const float* __restrict__ h,
                                               const float* __restrict__ w3b,
                                               const float* __restrict__ w4b,
                                               const float* __restrict__ w5b,
                                               const float* __restrict__ u5b,
                                               float* __restrict__ out) {
  __shared__ f16 ldsA[32768];  // rh2 tile: kt-planes {l0[128][32], l1'[128][32]}
  __shared__ f16 ldsB[32768];  // u5wb: same plane structure
  const int t = threadIdx.x;
  const int m0 = blockIdx.x * 128;
  const int wave = t >> 6;
  const int gs = (t & 3) ^ ((t >> 3) & 3);

  // ---- phase 0: issue B staging (lands under phase 1)
#pragma unroll
  for (int kt = 0; kt < 4; ++kt)
#pragma unroll
    for (int lb = 0; lb < 2; ++lb)
#pragma unroll
      for (int g = 0; g < 2; ++g) {
        const int row_ = g * 64 + (t >> 2);
        gload16(u5wb + (size_t)row_ * 256 + lb * 128 + kt * 32 + gs * 8,
                ldsB + kt * 8192 + lb * 4096 + g * 2048 + wave * 512);
      }

  // ---- phase 1: rh2 tile (ew1's exact op order) -> ldsA, staging layout
  {
    const int r_ = t >> 1;
    const int ch = t & 1;
    const int gr_ = m0 + r_;
    const int bb_ = gr_ & 31, node_ = gr_ >> 5;
    const float* prow = pre + (size_t)gr_ * 384 + 128;
    const float* urow = u3f + (size_t)gr_ * 128;
    const float* hrow = h + ((size_t)bb_ * 1024 + node_) * 128;
    const int swk = (r_ >> 1) & 3;
#pragma unroll
    for (int s = 0; s < 8; ++s) {
      const int c0 = ch * 64 + s * 8;
      const f32x4 p0 = *(const f32x4*)(prow + c0);
      const f32x4 p1 = *(const f32x4*)(prow + c0 + 4);
      const f32x4 u0 = *(const f32x4*)(urow + c0);
      const f32x4 u1 = *(const f32x4*)(urow + c0 + 4);
      const f32x4 h0 = *(const f32x4*)(hrow + c0);
      const f32x4 h1 = *(const f32x4*)(hrow + c0 + 4);
      const f32x4 b0 = *(const f32x4*)(w4b + c0);
      const f32x4 b1 = *(const f32x4*)(w4b + c0 + 4);
      f16 l0v[8], l1v[8];
#pragma unroll
      for (int j = 0; j < 4; ++j) {
        const float ra = sigmoidf_((p0[j] + b0[j]) + u0[j]);
        split2(ra * h0[j], l0v[j], l1v[j]);
        const float rb2 = sigmoidf_((p1[j] + b1[j]) + u1[j]);
        split2(rb2 * h1[j], l0v[4 + j], l1v[4 + j]);
      }
      const int kt = c0 >> 5;
      const int sw = ((c0 >> 3) & 3) ^ swk;
      *(f16x8*)&ldsA[kt * 8192 + r_ * 32 + sw * 8] = *(f16x8*)l0v;
      *(f16x8*)&ldsA[kt * 8192 + 4096 + r_ * 32 + sw * 8] = *(f16x8*)l1v;
    }
  }
  __syncthreads();

  // ---- phase 2: 16x16 GEMM from LDS (identical to r12)
  f32x4 aM[4][4], aC[4][4];
  ACCZ4(aM);
  ACCZ4(aC);
  {
    const int lane = t & 63;
    const int wr = wave >> 1, wn = wave & 1;
    const int frow = lane & 15;
    const int fk = lane >> 4;
    const int sl = fk ^ ((frow >> 1) & 3);
    for (int kt = 0; kt < 4; ++kt) {
      const f16* ap = ldsA + kt * 8192;
      const f16* bp = ldsB + kt * 8192;
      f16x8 a0[4], a1[4], b0[4], b1[4];
#pragma unroll
      for (int nf = 0; nf < 4; ++nf) {
        const int row = wn * 64 + nf * 16 + frow;
        b0[nf] = *(const f16x8*)&bp[row * 32 + sl * 8];
        b1[nf] = *(const f16x8*)&bp[4096 + row * 32 + sl * 8];
      }
#pragma unroll
      for (int mf = 0; mf < 4; ++mf) {
        const int row = wr * 64 + mf * 16 + frow;
        a0[mf] = *(const f16x8*)&ap[row * 32 + sl * 8];
        a1[mf] = *(const f16x8*)&ap[4096 + row * 32 + sl * 8];
      }
      __builtin_amdgcn_s_setprio(1);
#pragma unroll
      for (int mf = 0; mf < 4; ++mf)
#pragma unroll
        for (int nf = 0; nf < 4; ++nf) {
          aC[mf][nf] = __builtin_amdgcn_mfma_f32_16x16x32_f16(a0[mf], b1[nf],
                                                              aC[mf][nf], 0, 0, 0);
          aC[mf][nf] = __builtin_amdgcn_mfma_f32_16x16x32_f16(a1[mf], b0[nf],
                                                              aC[mf][nf], 0, 0, 0);
        }
#pragma unroll
      for (int mf = 0; mf < 4; ++mf)
#pragma unroll
        for (int nf = 0; nf < 4; ++nf)
          aM[mf][nf] = __builtin_amdgcn_mfma_f32_16x16x32_f16(a0[mf], b0[nf],
                                                              aM[mf][nf], 0, 0, 0);
      __builtin_amdgcn_s_setprio(0);
    }
  }

  // ---- epilogue (identical to r12)
  const int lane = t & 63;
  const int rb = m0 + (wave >> 1) * 64 + (lane >> 4) * 4;
  const int cb = (wave & 1) * 64 + (lane & 15);
#pragma unroll
  for (int mf = 0; mf < 4; ++mf)
#pragma unroll
    for (int nf = 0; nf < 4; ++nf)
#pragma unroll
      for (int j = 0; j < 4; ++j) {
        const int gr = rb + mf * 16 + j;
        const int gc = cb + nf * 16;
        const float v = aM[mf][nf][j] + aC[mf][nf][j] * CSCL;
        const float u5f = v + u5b[gc];  // np: U5 + u5b
        const float z = sigmoidf_((pre[(size_t)gr * 384 + gc] + w3b[gc]) +
                                  u3f[(size_t)gr * 128 + gc]);
        const float hv = tanhf((pre[(size_t)gr * 384 + 256 + gc] + w5b[gc]) + u5f);
        const int bb = gr & 31, node = gr >> 5;
        const size_t hi = ((size_t)bb * 1024 + node) * 128 + gc;
        const float hh = h[hi];
        out[hi] = (1.f - z) * hh + z * hv;  // np: (1-z)*h + z*hv
      }
}

// ================= pack h (fp32 [B][N][D]) -> hN2f 2-limb + X2 h-cols 2-limb
__global__ __launch_bounds__(256) void pack_h(const float* __restrict__ h,
                                              f16* __restrict__ hN2f,
                                              f16* __restrict__ X2) {
  __shared__ unsigned int lds01[128][33];
  const int t = threadIdx.x;
  const int b = blockIdx.y;
  const int n0 = blockIdx.x * 32;
#pragma unroll
  for (int i = 0; i < 16; ++i) {
    const int idx = i * 256 + t;
    const int nl = idx >> 7, d = idx & 127;
    const float v = h[((size_t)b * 1024 + n0 + nl) * 128 + d];
    f16 l0, l1;
    split2(v, l0, l1);
    const size_t xr = ((size_t)(n0 + nl) * 32 + b) * LDX + 256 + d;
    X2[xr] = l0;
    X2[xr + 384] = l1;
    lds01[d][nl] = (unsigned)bc16(l0) | ((unsigned)bc16(l1) << 16);
  }
  __syncthreads();
#pragma unroll
  for (int i = 0; i < 16; ++i) {
    const int idx = i * 256 + t;
    const int d = idx >> 5, nl = idx & 31;
    const unsigned pk = lds01[d][nl];
    f16* row = hN2f + (size_t)(b * 128 + d) * LDH + n0 + nl;
    row[0] = __builtin_bit_cast(f16, (unsigned short)(pk & 0xffffu));
    row[1024] = __builtin_bit_cast(f16, (unsigned short)(pk >> 16));
  }
}

// ================= init kernels
__global__ __launch_bounds__(256) void split_adjf(const float* __restrict__ src,
                                                  f16* __restrict__ dst) {
  const int i = blockIdx.x * 256 + threadIdx.x;  // 1M
  const int r = i >> 10, c = i & 1023;
  f16 l0, l1;
  split2(src[i], l0, l1);
  dst[(size_t)r * LDH + c] = l0;
  dst[(size_t)r * LDH + 1024 + c] = l1;
}

__global__ void build_wsm(const float* __restrict__ w3, const float* __restrict__ w4,
                          const float* __restrict__ w5, f16* __restrict__ Wsm) {
  const int k = blockIdx.x * 128 + threadIdx.x;  // 0..255
  const int j = blockIdx.y;                      // 0..383
  float v;
  if (j < 128) v = w3[j * 256 + k];
  else if (j < 256) v = w4[(j - 128) * 256 + k];
  else v = w5[(j - 256) * 256 + k];
  f16 l0, l1;
  split2(v, l0, l1);
  Wsm[(size_t)j * 512 + k] = l0;
  Wsm[(size_t)j * 512 + 256 + k] = l1;
}

__global__ void build_uw(const float* __restrict__ u, f16* __restrict__ dst) {
  const int i = blockIdx.x * 256 + threadIdx.x;  // 16384
  const int j = i >> 7, k = i & 127;
  f16 l0, l1;
  split2(u[i], l0, l1);
  dst[(size_t)j * 256 + k] = l0;
  dst[(size_t)j * 256 + 128 + k] = l1;
}

__global__ void sentinel(float* out, int n) {
  const int i = blockIdx.x * 256 + threadIdx.x;
  if (i < n) out[i] = 123456789.f;
}

extern "C" void kernel_launch(void* const* d_in, const int* in_sizes, int n_in,
                              void* d_out, int out_size, void* d_ws, size_t ws_size,
                              hipStream_t stream) {
  const float* input = (const float*)d_in[0];
  const float* Ain = (const float*)d_in[1];
  const float* Aout = (const float*)d_in[2];
  const float* w3w = (const float*)d_in[3];
  const float* w3b = (const float*)d_in[4];
  const float* u3w = (const float*)d_in[5];
  const float* u3b = (const float*)d_in[6];
  const float* w4w = (const float*)d_in[7];
  const float* w4b = (const float*)d_in[8];
  const float* w5w = (const float*)d_in[9];
  const float* w5b = (const float*)d_in[10];
  const float* u5wf = (const float*)d_in[11];
  const float* u5b = (const float*)d_in[12];
  // d_in[13] = time_step; fixed at 5 by the problem spec.

  char* ws = (char*)d_ws;
  size_t off = 0;
  auto alloc = [&](size_t bytes) -> void* {
    void* p = ws + off;
    off += (bytes + 255) & ~(size_t)255;
    return p;
  };
  f16* A2f = (f16*)alloc(2048ull * LDH * 2);   // 8.39 MB
  f16* hN2f = (f16*)alloc(4096ull * LDH * 2);  // 16.78 MB
  f16* X2 = (f16*)alloc(32768ull * LDX * 2);   // 50.33 MB
  f16* Wsm = (f16*)alloc(384ull * 512 * 2);
  f16* u3wb = (f16*)alloc(128ull * 256 * 2);
  f16* u5wb = (f16*)alloc(128ull * 256 * 2);
  float* pre = (float*)alloc(32768ull * 384 * 4);  // 50.33 MB
  float* u3f = (float*)alloc(32768ull * 128 * 4);  // 16.78 MB
  if (off > ws_size) {
    sentinel<<<dim3((out_size + 255) / 256), dim3(256), 0, stream>>>((float*)d_out, out_size);
    return;
  }

  split_adjf<<<dim3(4096), dim3(256), 0, stream>>>(Ain, A2f);
  split_adjf<<<dim3(4096), dim3(256), 0, stream>>>(Aout, A2f + 1024ull * LDH);
  build_wsm<<<dim3(2, 384), dim3(128), 0, stream>>>(w3w, w4w, w5w, Wsm);
  build_uw<<<dim3(64), dim3(256), 0, stream>>>(u3w, u3wb);
  build_uw<<<dim3(64), dim3(256), 0, stream>>>(u5wf, u5wb);

  float* out = (float*)d_out;
  const float* h = input;
  for (int step = 0; step < 5; ++step) {
    pack_h<<<dim3(32, 32), dim3(256), 0, stream>>>(h, hN2f, X2);
    adjf<<<dim3(32, 16), dim3(256), 0, stream>>>(A2f, hN2f, X2);
    densef<<<dim3(4, 256), dim3(256), 0, stream>>>(X2, Wsm, u3wb, u3b, pre, u3f);
    u5gf<<<dim3(256), dim3(256), 0, stream>>>(u5wb, pre, u3f, h, w3b, w4b, w5b, u5b,
                                              out);
    h = out;
  }
}

// Round 15
// 689.145 us; speedup vs baseline: 2.5215x; 2.5215x over previous
//
#include <hip/hip_runtime.h>
#include <cstdint>
#include <cstddef>

// GGNN on MI355X. Round 15: restoration of the measured-best configuration
// (round 9: 689.4us, absmax 0.02490234). 2-limb f16 (l1 pre-scaled 2^11),
// 3 products {01,10}->accC {00}->accM, v = accM + accC*2^-11; 128x128-tile
// GEMMs, 4 waves, 16x16x32 MFMA, dbuf 64KB, vmcnt(8), slot-XOR swizzle,
// 2 blocks/CU. Separate ew1 + u5g (r12's fusion was neutral; r9 measured best).
// Refuted this session (kept for the record):
//  - 8-phase/counted-vmcnt schedules: no wave slip under barriers (r5/r6)
//  - 32x32x16 MFMA: intrinsic bank conflicts w/ 32-elem-row planes (r13)
//  - wide 128x256 tile @1 block/CU: loses cross-block overlap (r11)
//  - unscaled l1: MFMA denormal flush kills the limb (r11)
//  - 3 blocks/CU via 48KB LDS: VGPR budget forces accumulator spill (r14)
// Layouts:
//   A2f [2048: Ain|Aout][ l0(1024) | l1'(1024) ]
//   hN2f[b*128+d][ l0 | l1' ]   (rh2 overlay)
//   X2  [n*32+b][ l0: m_in(128) m_out(128) h(128) | l1' same ]  (LDX 768)
//   Wsm [384: w3|w4|w5][ l0(256)|l1'(256) ]; u3wb/u5wb [128][ l0|l1' (128) ]

typedef _Float16 f16;
typedef __attribute__((ext_vector_type(8))) _Float16 f16x8;
typedef __attribute__((ext_vector_type(4))) float f32x4;

#define LDX 768
#define LDH 2048
#define CSCL 4.8828125e-4f  // 2^-11

static __device__ __forceinline__ void gload16(const void* g, void* l) {
  __builtin_amdgcn_global_load_lds(
      (const __attribute__((address_space(1))) void*)g,
      (__attribute__((address_space(3))) void*)l, 16, 0, 0);
}

static __device__ __forceinline__ float sigmoidf_(float x) {
  return 1.f / (1.f + expf(-x));
}

static __device__ __forceinline__ unsigned short bc16(f16 x) {
  return __builtin_bit_cast(unsigned short, x);
}

// split v into l0 + l1*2^-11 (l1 stored scaled; avoids f16 subnormals)
static __device__ __forceinline__ void split2(float v, f16& l0, f16& l1) {
  l0 = (f16)v;
  l1 = (f16)((v - (float)l0) * 2048.0f);
}

// ======== 2-limb f16 3-product GEMM core, 128x128 tile, 4 waves (2Mx2N) ======
// A: 128 rows, stride lda, limb l at col (abase + l*aLS + k); B: 128 rows,
// stride ldb, limb l at col (l*bLS + k). nkt = K/32. lds: 2 bufs x 16384 f16
// (A0,A1,B0,B1 planes of [128][32]). accM: main product (k ascending);
// accC: cross products (scaled 2^11).
static __device__ __forceinline__ void gemf(const f16* __restrict__ A, int lda,
                                            int aLS, int abase,
                                            const f16* __restrict__ B, int ldb,
                                            int bLS, int nkt, f16* lds,
                                            f32x4 (&aM)[4][4], f32x4 (&aC)[4][4]) {
  const int t = threadIdx.x;
  const int wave = t >> 6, lane = t & 63;
  const int wr = wave >> 1, wn = wave & 1;
  const int frow = lane & 15;
  const int fk = lane >> 4;                    // 0..3 (16B k-slot)
  const int sl = fk ^ ((frow >> 1) & 3);       // swizzled read slot
  const int gs = (t & 3) ^ ((t >> 3) & 3);     // inverse-swizzled global slot

  // 8 gloads/thread per K-tile: 2 limbs x 2 row-groups x (A,B)
#define STG(buf, kt)                                                          \
  _Pragma("unroll") for (int lb = 0; lb < 2; ++lb)                            \
  _Pragma("unroll") for (int g = 0; g < 2; ++g) {                             \
    const int row_ = g * 64 + (t >> 2);                                       \
    gload16(A + (size_t)row_ * lda + abase + lb * aLS + (kt) * 32 + gs * 8,   \
            lds + (buf) * 16384 + lb * 4096 + g * 2048 + wave * 512);         \
    gload16(B + (size_t)row_ * ldb + lb * bLS + (kt) * 32 + gs * 8,           \
            lds + (buf) * 16384 + 8192 + lb * 4096 + g * 2048 + wave * 512);  \
  }

  STG(0, 0);
  for (int kt = 0; kt < nkt; ++kt) {
    const int cur = kt & 1;
    if (kt + 1 < nkt) {
      STG(cur ^ 1, kt + 1);
      asm volatile("s_waitcnt vmcnt(8)" ::: "memory");  // current buf landed
    } else {
      asm volatile("s_waitcnt vmcnt(0)" ::: "memory");
    }
    __builtin_amdgcn_s_barrier();
    asm volatile("" ::: "memory");

    const f16* bp = lds + cur * 16384;
    f16x8 a0[4], a1[4], b0[4], b1[4];
#pragma unroll
    for (int nf = 0; nf < 4; ++nf) {
      const int row = wn * 64 + nf * 16 + frow;
      b0[nf] = *(const f16x8*)&bp[8192 + row * 32 + sl * 8];
      b1[nf] = *(const f16x8*)&bp[12288 + row * 32 + sl * 8];
    }
#pragma unroll
    for (int mf = 0; mf < 4; ++mf) {
      const int row = wr * 64 + mf * 16 + frow;
      a0[mf] = *(const f16x8*)&bp[row * 32 + sl * 8];
      a1[mf] = *(const f16x8*)&bp[4096 + row * 32 + sl * 8];
    }
    __builtin_amdgcn_s_setprio(1);
    // cross products (scale 2^11) -> accC
#pragma unroll
    for (int mf = 0; mf < 4; ++mf)
#pragma unroll
      for (int nf = 0; nf < 4; ++nf) {
        aC[mf][nf] = __builtin_amdgcn_mfma_f32_16x16x32_f16(a0[mf], b1[nf],
                                                            aC[mf][nf], 0, 0, 0);
        aC[mf][nf] = __builtin_amdgcn_mfma_f32_16x16x32_f16(a1[mf], b0[nf],
                                                            aC[mf][nf], 0, 0, 0);
      }
    // main product, k ascending -> accM
#pragma unroll
    for (int mf = 0; mf < 4; ++mf)
#pragma unroll
      for (int nf = 0; nf < 4; ++nf)
        aM[mf][nf] = __builtin_amdgcn_mfma_f32_16x16x32_f16(a0[mf], b0[nf],
                                                            aM[mf][nf], 0, 0, 0);
    __builtin_amdgcn_s_setprio(0);
    asm volatile("" ::: "memory");
    __builtin_amdgcn_s_barrier();  // all reads done -> buf reusable
  }
#undef STG
}

#define ACCZ4(a)                                   \
  _Pragma("unroll") for (int i_ = 0; i_ < 4; ++i_) \
  _Pragma("unroll") for (int j_ = 0; j_ < 4; ++j_) a[i_][j_] = {0.f, 0.f, 0.f, 0.f};

// ================= adjacency: M=2048(in|out), N=4096, K=1024
__global__ __launch_bounds__(256, 2) void adjf(const f16* __restrict__ A2f,
                                               const f16* __restrict__ hN2f,
                                               f16* __restrict__ X2) {
  __shared__ f16 lds[32768];
  const int m0 = blockIdx.y * 128;
  const int n0 = blockIdx.x * 128;
  f32x4 aM[4][4], aC[4][4];
  ACCZ4(aM);
  ACCZ4(aC);
  gemf(A2f + (size_t)m0 * LDH, LDH, 1024, 0, hN2f + (size_t)n0 * LDH, LDH, 1024,
       32, lds, aM, aC);

  const int lane = threadIdx.x & 63, wave = threadIdx.x >> 6;
  const int rb = m0 + (wave >> 1) * 64 + (lane >> 4) * 4;
  const int cb = n0 + (wave & 1) * 64 + (lane & 15);
#pragma unroll
  for (int mf = 0; mf < 4; ++mf)
#pragma unroll
    for (int nf = 0; nf < 4; ++nf)
#pragma unroll
      for (int j = 0; j < 4; ++j) {
        const int gr = rb + mf * 16 + j;
        const int gc = cb + nf * 16;
        const float v = aM[mf][nf][j] + aC[mf][nf][j] * CSCL;
        const int node = gr & 1023;
        const int coff = (gr >> 10) * 128;  // 0: m_in, 128: m_out
        const int bb = gc >> 7, d = gc & 127;
        f16* px = X2 + ((size_t)node * 32 + bb) * LDX + coff + d;
        f16 l0, l1;
        split2(v, l0, l1);
        px[0] = l0;
        px[384] = l1;
      }
}

// ================= dense: bx<3 -> pre[.][bx*128..]; bx==3 -> u3f (+u3b)
__global__ __launch_bounds__(256, 2) void densef(const f16* __restrict__ X2,
                                                 const f16* __restrict__ Wsm,
                                                 const f16* __restrict__ u3wb,
                                                 const float* __restrict__ u3b,
                                                 float* __restrict__ pre,
                                                 float* __restrict__ u3f) {
  __shared__ f16 lds[32768];
  const int m0 = blockIdx.y * 128;
  const int bx = blockIdx.x;
  f32x4 aM[4][4], aC[4][4];
  ACCZ4(aM);
  ACCZ4(aC);
  const int lane = threadIdx.x & 63, wave = threadIdx.x >> 6;
  const int rb = m0 + (wave >> 1) * 64 + (lane >> 4) * 4;
  const int cb = (wave & 1) * 64 + (lane & 15);
  if (bx < 3) {
    gemf(X2 + (size_t)m0 * LDX, LDX, 384, 0, Wsm + (size_t)bx * 128 * 512, 512, 256,
         8, lds, aM, aC);
#pragma unroll
    for (int mf = 0; mf < 4; ++mf)
#pragma unroll
      for (int nf = 0; nf < 4; ++nf)
#pragma unroll
        for (int j = 0; j < 4; ++j)
          pre[(size_t)(rb + mf * 16 + j) * 384 + bx * 128 + cb + nf * 16] =
              aM[mf][nf][j] + aC[mf][nf][j] * CSCL;
  } else {
    gemf(X2 + (size_t)m0 * LDX, LDX, 384, 256, u3wb, 256, 128, 4, lds, aM, aC);
#pragma unroll
    for (int mf = 0; mf < 4; ++mf)
#pragma unroll
      for (int nf = 0; nf < 4; ++nf)
#pragma unroll
        for (int j = 0; j < 4; ++j) {
          const int gc = cb + nf * 16;
          const float v = aM[mf][nf][j] + aC[mf][nf][j] * CSCL;
          // np: u3 = (h@u3w^T) + u3b, rounded once
          u3f[(size_t)(rb + mf * 16 + j) * 128 + gc] = v + u3b[gc];
        }
  }
}

// ================= u5 GEMM + fused ew2 epilogue (z, hv, h' -> out)
__global__ __launch_bounds__(256, 2) void u5g(const f16* __restrict__ rh2,
                                              const f16* __restrict__ u5wb,
                                              const float* __restrict__ pre,
                                              const float* __restrict__ u3f,
                                              const float* __restrict__ h,
                                              const float* __restrict__ w3b,
                                              const float* __restrict__ w5b,
                                              const float* __restrict__ u5b,
                                              float* __restrict__ out) {
  __shared__ f16 lds[32768];
  const int m0 = blockIdx.x * 128;
  f32x4 aM[4][4], aC[4][4];
  ACCZ4(aM);
  ACCZ4(aC);
  gemf(rh2 + (size_t)m0 * 256, 256, 128, 0, u5wb, 256, 128, 4, lds, aM, aC);

  const int lane = threadIdx.x & 63, wave = threadIdx.x >> 6;
  const int rb = m0 + (wave >> 1) * 64 + (lane >> 4) * 4;
  const int cb = (wave & 1) * 64 + (lane & 15);
#pragma unroll
  for (int mf = 0; mf < 4; ++mf)
#pragma unroll
    for (int nf = 0; nf < 4; ++nf)
#pragma unroll
      for (int j = 0; j < 4; ++j) {
        const int gr = rb + mf * 16 + j;
        const int gc = cb + nf * 16;
        const float v = aM[mf][nf][j] + aC[mf][nf][j] * CSCL;
        const float u5f = v + u5b[gc];  // np: U5 + u5b
        const float z = sigmoidf_((pre[(size_t)gr * 384 + gc] + w3b[gc]) +
                                  u3f[(size_t)gr * 128 + gc]);
        const float hv = tanhf((pre[(size_t)gr * 384 + 256 + gc] + w5b[gc]) + u5f);
        const int bb = gr & 31, node = gr >> 5;
        const size_t hi = ((size_t)bb * 1024 + node) * 128 + gc;
        const float hh = h[hi];
        out[hi] = (1.f - z) * hh + z * hv;  // np: (1-z)*h + z*hv
      }
}

// ================= pack h (fp32 [B][N][D]) -> hN2f 2-limb + X2 h-cols 2-limb
__global__ __launch_bounds__(256) void pack_h(const float* __restrict__ h,
                                              f16* __restrict__ hN2f,
                                              f16* __restrict__ X2) {
  __shared__ unsigned int lds01[128][33];
  const int t = threadIdx.x;
  const int b = blockIdx.y;
  const int n0 = blockIdx.x * 32;
#pragma unroll
  for (int i = 0; i < 16; ++i) {
    const int idx = i * 256 + t;
    const int nl = idx >> 7, d = idx & 127;
    const float v = h[((size_t)b * 1024 + n0 + nl) * 128 + d];
    f16 l0, l1;
    split2(v, l0, l1);
    const size_t xr = ((size_t)(n0 + nl) * 32 + b) * LDX + 256 + d;
    X2[xr] = l0;
    X2[xr + 384] = l1;
    lds01[d][nl] = (unsigned)bc16(l0) | ((unsigned)bc16(l1) << 16);
  }
  __syncthreads();
#pragma unroll
  for (int i = 0; i < 16; ++i) {
    const int idx = i * 256 + t;
    const int d = idx >> 5, nl = idx & 31;
    const unsigned pk = lds01[d][nl];
    f16* row = hN2f + (size_t)(b * 128 + d) * LDH + n0 + nl;
    row[0] = __builtin_bit_cast(f16, (unsigned short)(pk & 0xffffu));
    row[1024] = __builtin_bit_cast(f16, (unsigned short)(pk >> 16));
  }
}

// ================= elementwise: r gate -> rh2 (2-limb f16)
__global__ __launch_bounds__(256) void ew1(const float* __restrict__ pre,
                                           const float* __restrict__ u3f,
                                           const float* __restrict__ h,
                                           const float* __restrict__ w4b,
                                           f16* __restrict__ rh2) {
  const int e4 = blockIdx.x * 256 + threadIdx.x;
  const int r = e4 >> 5;
  const int dq = (e4 & 31) * 4;
  const int b = r & 31, n = r >> 5;
  const f32x4 p = *(const f32x4*)(pre + (size_t)r * 384 + 128 + dq);
  const f32x4 uf = *(const f32x4*)(u3f + (size_t)r * 128 + dq);
  const f32x4 hh = *(const f32x4*)(h + ((size_t)b * 1024 + n) * 128 + dq);
  const f32x4 b4 = *(const f32x4*)(w4b + dq);
  f16 o0[4], o1[4];
#pragma unroll
  for (int j = 0; j < 4; ++j) {
    const float rr = sigmoidf_((p[j] + b4[j]) + uf[j]);
    const float v = rr * hh[j];
    split2(v, o0[j], o1[j]);
  }
  *(ulong1*)&rh2[(size_t)r * 256 + dq] = *(ulong1*)o0;
  *(ulong1*)&rh2[(size_t)r * 256 + 128 + dq] = *(ulong1*)o1;
}

// ================= init kernels
__global__ __launch_bounds__(256) void split_adjf(const float* __restrict__ src,
                                                  f16* __restrict__ dst) {
  const int i = blockIdx.x * 256 + threadIdx.x;  // 1M
  const int r = i >> 10, c = i & 1023;
  f16 l0, l1;
  split2(src[i], l0, l1);
  dst[(size_t)r * LDH + c] = l0;
  dst[(size_t)r * LDH + 1024 + c] = l1;
}

__global__ void build_wsm(const float* __restrict__ w3, const float* __restrict__ w4,
                          const float* __restrict__ w5, f16* __restrict__ Wsm) {
  const int k = blockIdx.x * 128 + threadIdx.x;  // 0..255
  const int j = blockIdx.y;                      // 0..383
  float v;
  if (j < 128) v = w3[j * 256 + k];
  else if (j < 256) v = w4[(j - 128) * 256 + k];
  else v = w5[(j - 256) * 256 + k];
  f16 l0, l1;
  split2(v, l0, l1);
  Wsm[(size_t)j * 512 + k] = l0;
  Wsm[(size_t)j * 512 + 256 + k] = l1;
}

__global__ void build_uw(const float* __restrict__ u, f16* __restrict__ dst) {
  const int i = blockIdx.x * 256 + threadIdx.x;  // 16384
  const int j = i >> 7, k = i & 127;
  f16 l0, l1;
  split2(u[i], l0, l1);
  dst[(size_t)j * 256 + k] = l0;
  dst[(size_t)j * 256 + 128 + k] = l1;
}

__global__ void sentinel(float* out, int n) {
  const int i = blockIdx.x * 256 + threadIdx.x;
  if (i < n) out[i] = 123456789.f;
}

extern "C" void kernel_launch(void* const* d_in, const int* in_sizes, int n_in,
                              void* d_out, int out_size, void* d_ws, size_t ws_size,
                              hipStream_t stream) {
  const float* input = (const float*)d_in[0];
  const float* Ain = (const float*)d_in[1];
  const float* Aout = (const float*)d_in[2];
  const float* w3w = (const float*)d_in[3];
  const float* w3b = (const float*)d_in[4];
  const float* u3w = (const float*)d_in[5];
  const float* u3b = (const float*)d_in[6];
  const float* w4w = (const float*)d_in[7];
  const float* w4b = (const float*)d_in[8];
  const float* w5w = (const float*)d_in[9];
  const float* w5b = (const float*)d_in[10];
  const float* u5wf = (const float*)d_in[11];
  const float* u5b = (const float*)d_in[12];
  // d_in[13] = time_step; fixed at 5 by the problem spec.

  char* ws = (char*)d_ws;
  size_t off = 0;
  auto alloc = [&](size_t bytes) -> void* {
    void* p = ws + off;
    off += (bytes + 255) & ~(size_t)255;
    return p;
  };
  f16* A2f = (f16*)alloc(2048ull * LDH * 2);    // 8.39 MB
  f16* hN2f = (f16*)alloc(4096ull * LDH * 2);   // 16.78 MB (rh2 overlay)
  f16* X2 = (f16*)alloc(32768ull * LDX * 2);    // 50.33 MB
  f16* Wsm = (f16*)alloc(384ull * 512 * 2);
  f16* u3wb = (f16*)alloc(128ull * 256 * 2);
  f16* u5wb = (f16*)alloc(128ull * 256 * 2);
  float* pre = (float*)alloc(32768ull * 384 * 4);  // 50.33 MB
  float* u3f = (float*)alloc(32768ull * 128 * 4);  // 16.78 MB
  f16* rh2 = hN2f;  // overlay: ew1 writes after adjf read hN2f; pack_h rewrites
  if (off > ws_size) {
    sentinel<<<dim3((out_size + 255) / 256), dim3(256), 0, stream>>>((float*)d_out, out_size);
    return;
  }

  split_adjf<<<dim3(4096), dim3(256), 0, stream>>>(Ain, A2f);
  split_adjf<<<dim3(4096), dim3(256), 0, stream>>>(Aout, A2f + 1024ull * LDH);
  build_wsm<<<dim3(2, 384), dim3(128), 0, stream>>>(w3w, w4w, w5w, Wsm);
  build_uw<<<dim3(64), dim3(256), 0, stream>>>(u3w, u3wb);
  build_uw<<<dim3(64), dim3(256), 0, stream>>>(u5wf, u5wb);

  float* out = (float*)d_out;
  const float* h = input;
  for (int step = 0; step < 5; ++step) {
    pack_h<<<dim3(32, 32), dim3(256), 0, stream>>>(h, hN2f, X2);
    adjf<<<dim3(32, 16), dim3(256), 0, stream>>>(A2f, hN2f, X2);
    densef<<<dim3(4, 256), dim3(256), 0, stream>>>(X2, Wsm, u3wb, u3b, pre, u3f);
    ew1<<<dim3(4096), dim3(256), 0, stream>>>(pre, u3f, h, w4b, rh2);
    u5g<<<dim3(256), dim3(256), 0, stream>>>(rh2, u5wb, pre, u3f, h, w3b, w5b, u5b, out);
    h = out;
  }
}